// Round 12
// baseline (866.336 us; speedup 1.0000x reference)
//
#include <hip/hip_runtime.h>
#include <hip/hip_bf16.h>
#include <math.h>

#define DHID 128
#define SH 8                 // nodes per bucket = 256
#define CAPSH 13             // staged capacity per bucket = 8192 (avg fill ~4096)

typedef __attribute__((ext_vector_type(8))) short bf16x8;
typedef __attribute__((ext_vector_type(4))) float f32x4;

__device__ __forceinline__ int atomAddI(int* p, int v) {
    return __hip_atomic_fetch_add(p, v, __ATOMIC_RELAXED, __HIP_MEMORY_SCOPE_AGENT);
}
__device__ __forceinline__ float bf_lo(unsigned u) { return __uint_as_float(u << 16); }
__device__ __forceinline__ float bf_hi(unsigned u) { return __uint_as_float(u & 0xffff0000u); }
__device__ __forceinline__ float bf_us(unsigned short u) { return __uint_as_float((unsigned)u << 16); }
__device__ __forceinline__ unsigned short bf16_1(float f) {
    unsigned u = __float_as_uint(f);
    u += 0x7fffu + ((u >> 16) & 1u);   // RNE
    return (unsigned short)(u >> 16);
}
__device__ __forceinline__ unsigned pack_bf16x2(float a, float b) {
    unsigned ua = __float_as_uint(a);
    unsigned ub = __float_as_uint(b);
    ua = (ua + 0x7fffu + ((ua >> 16) & 1u)) >> 16;
    ub = (ub + 0x7fffu + ((ub >> 16) & 1u)) & 0xffff0000u;
    return ua | ub;
}

// ---- phase 1 (single pass): bin edges via global bucket cursors ----
// blocks >= nb_bin do the weight bf16 prep (independent work folded in).
// staged record: src (bits 0..23) | dst-within-bucket (bits 24..31)
__global__ __launch_bounds__(256) void bin_edges(const int* __restrict__ src,
                                                 const int* __restrict__ dst,
                                                 int* __restrict__ bcur,
                                                 unsigned* __restrict__ staged,
                                                 const float* __restrict__ W1,
                                                 const float* __restrict__ W2,
                                                 const float* __restrict__ Wih,
                                                 unsigned short* __restrict__ Wt1,
                                                 unsigned short* __restrict__ Wt2,
                                                 unsigned short* __restrict__ Wihb,
                                                 int E, int nb_bin) {
    int t = threadIdx.x;
    if (blockIdx.x >= nb_bin) {
        int idx = (blockIdx.x - nb_bin) * 256 + t;
        if (idx < 16384) {
            int k = idx >> 7, n = idx & 127;
            Wt1[n * 128 + k] = bf16_1(W1[idx]);
        } else if (idx < 32768) {
            int j = idx - 16384;
            int k = j >> 7, n = j & 127;
            Wt2[n * 128 + k] = bf16_1(W2[j]);
        } else if (idx < 32768 + 49152) {
            int j = idx - 32768;
            Wihb[j] = bf16_1(Wih[j]);
        }
        return;
    }
    int e = blockIdx.x * 256 + t;
    if (e >= E) return;
    int s = src[e], d = dst[e];
    int b = d >> SH;
    int pos = atomAddI(&bcur[b], 1);
    staged[((size_t)b << CAPSH) + pos] =
        (unsigned)s | ((unsigned)(d & ((1 << SH) - 1)) << 24);
}

// ---- phase 2: per bucket — global base (reduction over bcur), node histogram
//      + scan (-> off, dinv), then scatter into the bucket's CSR window ----
__global__ __launch_bounds__(256) void scatter_csr(const unsigned* __restrict__ staged,
                                                   const int* __restrict__ bcur,
                                                   int* __restrict__ off,
                                                   float* __restrict__ dinv,
                                                   int* __restrict__ rec,
                                                   int N, int E, int NB) {
    __shared__ int sh[256];
    __shared__ int curs[256];
    __shared__ int hist[256];
    int t = threadIdx.x;
    int b = blockIdx.x;
    int node0 = b << SH;

    // base = sum of bcur[0..b-1]
    int s0 = (t < b) ? bcur[t] : 0;
    int s1 = (256 + t < b) ? bcur[256 + t] : 0;
    int s = s0 + s1;
#pragma unroll
    for (int o = 1; o < 64; o <<= 1) s += __shfl_xor(s, o);
    if ((t & 63) == 0) sh[t >> 6] = s;
    __syncthreads();
    int base = sh[0] + sh[1] + sh[2] + sh[3];
    __syncthreads();

    // per-node histogram of this bucket's staged records
    hist[t] = 0;
    __syncthreads();
    int cnt_b = bcur[b];
    const unsigned* st = staged + ((size_t)b << CAPSH);
    for (int j = t; j < cnt_b; j += 256)
        atomicAdd(&hist[st[j] >> 24], 1);
    __syncthreads();
    int v = hist[t];
    sh[t] = v;
    __syncthreads();
#pragma unroll
    for (int o = 1; o < 256; o <<= 1) {
        int x = (t >= o) ? sh[t - o] : 0;
        __syncthreads();
        sh[t] += x;
        __syncthreads();
    }
    int excl = sh[t] - v;
    int node = node0 + t;
    if (node < N) {
        off[node] = base + excl;
        dinv[node] = rsqrtf((float)v + 1.0f);
    }
    if (b == NB - 1 && t == 0) off[N] = E;
    curs[t] = base + excl;
    __syncthreads();
    for (int j = t; j < cnt_b; j += 256) {
        unsigned w = st[j];
        int dl = w >> 24;
        int pos = atomicAdd(&curs[dl], 1);
        rec[pos] = (int)(w & 0xFFFFFFu);
    }
}

// ---------------- MFMA GEMM: Y_bf16[rows,128] = X[rows,128] @ Wt^T ----------------
// 64 rows/block, 4 waves; epilogue via LDS transpose -> coalesced uint4 stores.
__global__ __launch_bounds__(256) void gemm_mfma(const void* __restrict__ Xv,
                                                 const unsigned short* __restrict__ Wt,
                                                 unsigned short* __restrict__ Y,
                                                 int N, int x_is_bf16,
                                                 int wstride, int ystride) {
    __shared__ unsigned short Xs[64 * 136];
    __shared__ unsigned short Ws[128 * 136];
    const int tid = threadIdx.x;
    const unsigned short* Wg = Wt + (size_t)blockIdx.y * wstride;
    unsigned short* Yg = Y + (size_t)blockIdx.y * ystride;

    {
        const uint4* W4 = (const uint4*)Wg;
#pragma unroll
        for (int i = 0; i < 8; i++) {
            int idx = tid + i * 256;
            int r = idx >> 4, c8 = idx & 15;
            *(uint4*)&Ws[r * 136 + c8 * 8] = W4[idx];
        }
    }
    const int row0 = blockIdx.x * 64;
    if (x_is_bf16) {
        const uint4* X4 = (const uint4*)Xv;
#pragma unroll
        for (int i = 0; i < 4; i++) {
            int idx = tid + i * 256;
            int r = idx >> 4, c8 = idx & 15;
            uint4 v = make_uint4(0u, 0u, 0u, 0u);
            if (row0 + r < N) v = X4[(size_t)(row0 + r) * 16 + c8];
            *(uint4*)&Xs[r * 136 + c8 * 8] = v;
        }
    } else {
        const float4* X4 = (const float4*)Xv;
#pragma unroll
        for (int i = 0; i < 8; i++) {
            int idx = tid + i * 256;
            int r = idx >> 5, c4 = idx & 31;
            float4 v = make_float4(0.f, 0.f, 0.f, 0.f);
            if (row0 + r < N) v = X4[(size_t)(row0 + r) * 32 + c4];
            uint2 pk = make_uint2(pack_bf16x2(v.x, v.y), pack_bf16x2(v.z, v.w));
            *(uint2*)&Xs[r * 136 + c4 * 4] = pk;
        }
    }
    __syncthreads();

    const int lane = tid & 63;
    const int wv = tid >> 6;
    const int m = lane & 15, quad = lane >> 4;
    const int wrow = wv * 16;

    f32x4 acc[8];
#pragma unroll
    for (int i = 0; i < 8; i++) acc[i] = (f32x4){0.f, 0.f, 0.f, 0.f};

#pragma unroll
    for (int kc = 0; kc < 4; kc++) {
        bf16x8 a = *(const bf16x8*)&Xs[(wrow + m) * 136 + kc * 32 + quad * 8];
#pragma unroll
        for (int nt = 0; nt < 8; nt++) {
            bf16x8 b = *(const bf16x8*)&Ws[(nt * 16 + m) * 136 + kc * 32 + quad * 8];
            acc[nt] = __builtin_amdgcn_mfma_f32_16x16x32_bf16(a, b, acc[nt], 0, 0, 0);
        }
    }

#pragma unroll
    for (int r = 0; r < 4; r++) {
        int lrow = wrow + quad * 4 + r;
#pragma unroll
        for (int nt = 0; nt < 8; nt++)
            Xs[lrow * 136 + nt * 16 + m] = bf16_1(acc[nt][r]);
    }
    __syncthreads();
#pragma unroll
    for (int i = 0; i < 4; i++) {
        int idx = tid + i * 256;
        int r = idx >> 4, c8 = idx & 15;
        if (row0 + r < N)
            *(uint4*)&Yg[(size_t)(row0 + r) * DHID + c8 * 8] =
                *(const uint4*)&Xs[r * 136 + c8 * 8];
    }
}

// ---------------- CSR aggregate: quarter-wave uint4 gathers, bf16 out ----------------
// float2 accumulators (packed f32 math) + software-pipelined rec loads.
__global__ __launch_bounds__(256) void aggregate(const unsigned short* __restrict__ A,
                                                 const float* __restrict__ dinv,
                                                 const int* __restrict__ off,
                                                 const int* __restrict__ rec,
                                                 const float* __restrict__ bias,
                                                 unsigned short* __restrict__ Bout,
                                                 int N, int mode) {
    int node = blockIdx.x * 4 + (threadIdx.x >> 6);
    if (node >= N) return;
    int lane = threadIdx.x & 63;
    int q  = lane >> 4;
    int ql = lane & 15;
    float di = dinv[node];
    float2 acc[4];
    if (q == 0) {
        float s = di * di;
        uint4 v = ((const uint4*)(A + (size_t)node * DHID))[ql];
        const float4* bb = (const float4*)(bias + ql * 8);
        float4 b0 = bb[0], b1 = bb[1];
        acc[0] = make_float2(bf_lo(v.x) * s + b0.x, bf_hi(v.x) * s + b0.y);
        acc[1] = make_float2(bf_lo(v.y) * s + b0.z, bf_hi(v.y) * s + b0.w);
        acc[2] = make_float2(bf_lo(v.z) * s + b1.x, bf_hi(v.z) * s + b1.y);
        acc[3] = make_float2(bf_lo(v.w) * s + b1.z, bf_hi(v.w) * s + b1.w);
    } else {
#pragma unroll
        for (int i = 0; i < 4; i++) acc[i] = make_float2(0.f, 0.f);
    }
    int j = off[node] + q;
    int jend = off[node + 1];
    if (j + 4 < jend) {
        int s0 = rec[j], s1 = rec[j + 4];
        for (; j + 12 < jend; j += 8) {
            int n0 = rec[j + 8], n1 = rec[j + 12];      // prefetch next pair
            uint4 v0 = ((const uint4*)(A + (size_t)s0 * DHID))[ql];
            uint4 v1 = ((const uint4*)(A + (size_t)s1 * DHID))[ql];
            float w0 = dinv[s0] * di;
            float w1 = dinv[s1] * di;
            acc[0].x += bf_lo(v0.x) * w0 + bf_lo(v1.x) * w1;
            acc[0].y += bf_hi(v0.x) * w0 + bf_hi(v1.x) * w1;
            acc[1].x += bf_lo(v0.y) * w0 + bf_lo(v1.y) * w1;
            acc[1].y += bf_hi(v0.y) * w0 + bf_hi(v1.y) * w1;
            acc[2].x += bf_lo(v0.z) * w0 + bf_lo(v1.z) * w1;
            acc[2].y += bf_hi(v0.z) * w0 + bf_hi(v1.z) * w1;
            acc[3].x += bf_lo(v0.w) * w0 + bf_lo(v1.w) * w1;
            acc[3].y += bf_hi(v0.w) * w0 + bf_hi(v1.w) * w1;
            s0 = n0; s1 = n1;
        }
        // drain the prefetched pair
        {
            uint4 v0 = ((const uint4*)(A + (size_t)s0 * DHID))[ql];
            uint4 v1 = ((const uint4*)(A + (size_t)s1 * DHID))[ql];
            float w0 = dinv[s0] * di;
            float w1 = dinv[s1] * di;
            acc[0].x += bf_lo(v0.x) * w0 + bf_lo(v1.x) * w1;
            acc[0].y += bf_hi(v0.x) * w0 + bf_hi(v1.x) * w1;
            acc[1].x += bf_lo(v0.y) * w0 + bf_lo(v1.y) * w1;
            acc[1].y += bf_hi(v0.y) * w0 + bf_hi(v1.y) * w1;
            acc[2].x += bf_lo(v0.z) * w0 + bf_lo(v1.z) * w1;
            acc[2].y += bf_hi(v0.z) * w0 + bf_hi(v1.z) * w1;
            acc[3].x += bf_lo(v0.w) * w0 + bf_lo(v1.w) * w1;
            acc[3].y += bf_hi(v0.w) * w0 + bf_hi(v1.w) * w1;
            j += 8;
        }
    }
    if (j < jend) {
        int s0 = rec[j];
        uint4 v0 = ((const uint4*)(A + (size_t)s0 * DHID))[ql];
        float w0 = dinv[s0] * di;
        acc[0].x += bf_lo(v0.x) * w0;
        acc[0].y += bf_hi(v0.x) * w0;
        acc[1].x += bf_lo(v0.y) * w0;
        acc[1].y += bf_hi(v0.y) * w0;
        acc[2].x += bf_lo(v0.z) * w0;
        acc[2].y += bf_hi(v0.z) * w0;
        acc[3].x += bf_lo(v0.w) * w0;
        acc[3].y += bf_hi(v0.w) * w0;
    }
#pragma unroll
    for (int i = 0; i < 4; i++) {
        acc[i].x += __shfl_xor(acc[i].x, 16);
        acc[i].y += __shfl_xor(acc[i].y, 16);
        acc[i].x += __shfl_xor(acc[i].x, 32);
        acc[i].y += __shfl_xor(acc[i].y, 32);
    }
    if (q == 0) {
        if (mode == 1) {
#pragma unroll
            for (int i = 0; i < 4; i++) {
                acc[i].x = fmaxf(acc[i].x, 0.f);
                acc[i].y = fmaxf(acc[i].y, 0.f);
            }
        }
        uint4 pk;
        pk.x = pack_bf16x2(acc[0].x, acc[0].y);
        pk.y = pack_bf16x2(acc[1].x, acc[1].y);
        pk.z = pack_bf16x2(acc[2].x, acc[2].y);
        pk.w = pack_bf16x2(acc[3].x, acc[3].y);
        ((uint4*)(Bout + (size_t)node * DHID))[ql] = pk;
    }
}

// ---------------- pool: per-graph mean (bf16 input) ----------------
__global__ __launch_bounds__(256) void pool_mean(const unsigned short* __restrict__ B,
                                                 const int* __restrict__ batch,
                                                 float* __restrict__ g, int N, int G) {
    __shared__ int se[2];
    __shared__ float red[128];
    const int t = threadIdx.x;
    const int gr = blockIdx.x;
    if (t < 2) {
        int target = gr + t, lo = 0, hi = N;
        while (lo < hi) {
            int mid = (lo + hi) >> 1;
            if (batch[mid] < target) lo = mid + 1; else hi = mid;
        }
        se[t] = lo;
    }
    __syncthreads();
    const int s = se[0], e = se[1];
    const int col = t & 127, rh = t >> 7;
    float sum = 0.f;
    for (int r = s + rh; r < e; r += 2) sum += bf_us(B[(size_t)r * DHID + col]);
    if (rh == 1) red[col] = sum;
    __syncthreads();
    if (rh == 0) {
        float tot = sum + red[col];
        g[(size_t)gr * DHID + col] = tot / fmaxf((float)(e - s), 1.0f);
    }
}

// ---------------- gates + relu + layernorm + linear ----------------
__global__ __launch_bounds__(128) void gate_ln_head(const unsigned short* __restrict__ gi,
                                                    const float* __restrict__ b_ih,
                                                    const float* __restrict__ b_hh,
                                                    const float* __restrict__ W_lin,
                                                    const float* __restrict__ b_lin,
                                                    float* __restrict__ out, int G) {
    __shared__ float red[2];
    const int t = threadIdx.x;
    const int g = blockIdx.x;

    float d0 = bf_us(gi[(size_t)g * DHID + t]);
    float d1 = bf_us(gi[(size_t)(G + g) * DHID + t]);
    float d2 = bf_us(gi[(size_t)(2 * G + g) * DHID + t]);

    float rg = 1.f / (1.f + expf(-(d0 + b_ih[t] + b_hh[t])));
    float zg = 1.f / (1.f + expf(-(d1 + b_ih[128 + t] + b_hh[128 + t])));
    float ng = tanhf(d2 + b_ih[256 + t] + rg * b_hh[256 + t]);
    float y = fmaxf((1.f - zg) * ng, 0.f);

    auto blockSum = [&](float v) -> float {
#pragma unroll
        for (int o = 1; o < 64; o <<= 1) v += __shfl_xor(v, o);
        __syncthreads();
        if ((t & 63) == 0) red[t >> 6] = v;
        __syncthreads();
        return red[0] + red[1];
    };

    float mu = blockSum(y) * (1.f / 128.f);
    float dy = y - mu;
    float var = blockSum(dy * dy) * (1.f / 128.f);
    float yn = dy * rsqrtf(var + 1e-5f);
    float tot = blockSum(yn * W_lin[t]);
    if (t == 0) out[g] = tot + b_lin[0];
}

extern "C" void kernel_launch(void* const* d_in, const int* in_sizes, int n_in,
                              void* d_out, int out_size, void* d_ws, size_t ws_size,
                              hipStream_t stream) {
    const float* x     = (const float*)d_in[0];
    const int*   ei    = (const int*)d_in[1];
    const int*   batch = (const int*)d_in[2];
    const float* W1    = (const float*)d_in[3];
    const float* b1    = (const float*)d_in[4];
    const float* W2    = (const float*)d_in[5];
    const float* b2    = (const float*)d_in[6];
    const float* W_ih  = (const float*)d_in[7];
    // d_in[8] = W_hh unused (h0 == 0)
    const float* b_ih  = (const float*)d_in[9];
    const float* b_hh  = (const float*)d_in[10];
    const float* W_lin = (const float*)d_in[11];
    const float* b_lin = (const float*)d_in[12];
    float* out = (float*)d_out;

    const int N = in_sizes[0] / DHID;
    const int E = in_sizes[1] / 2;
    const int G = out_size;
    const int* src = ei;
    const int* dst = ei + E;
    const int NB = (N + (1 << SH) - 1) >> SH;   // buckets (<= 512)

    auto align256 = [](size_t v) { return (v + 255) & ~(size_t)255; };
    char* p = (char*)d_ws;
    size_t used = 0;
    auto carve = [&](size_t bytes) -> char* {
        char* q = p + used;
        used += align256(bytes);
        return q;
    };

    int*   off    = (int*)carve(((size_t)N + 1) * 4);
    int*   bcur   = (int*)carve(512 * 4);
    float* dinv   = (float*)carve((size_t)N * 4);
    unsigned* staged = (unsigned*)carve(((size_t)NB << CAPSH) * 4);
    int*   rec    = (int*)carve((size_t)E * 4);
    float* gbuf   = (float*)carve((size_t)G * DHID * 4);
    unsigned short* Wt1  = (unsigned short*)carve((size_t)128 * 128 * 2);
    unsigned short* Wt2  = (unsigned short*)carve((size_t)128 * 128 * 2);
    unsigned short* Wihb = (unsigned short*)carve((size_t)3 * 128 * 128 * 2);
    unsigned short* gib  = (unsigned short*)carve((size_t)3 * G * DHID * 2);
    unsigned short* A    = (unsigned short*)carve((size_t)N * DHID * 2);   // bf16
    unsigned short* B1b  = (unsigned short*)carve((size_t)N * DHID * 2);   // bf16, relu'd
    size_t matB = (size_t)N * DHID * 2;
    unsigned short* B2b;
    if (ws_size >= used + matB) {
        B2b = (unsigned short*)carve(matB);
    } else {
        B2b = (unsigned short*)d_in[0];   // x fully consumed by gemm-1 before agg-2 writes
    }

    dim3 blk(256);
    int nb_g  = (N + 63) / 64;
    int nb_ag = (N + 3) / 4;
    int nb_bin = (E + 255) / 256;
    int nb_wp  = (81920 + 255) / 256;

    // ---- CSR build (3 dispatches; weight prep folded into bin_edges) ----
    hipMemsetAsync(bcur, 0, (size_t)NB * 4, stream);
    bin_edges<<<nb_bin + nb_wp, blk, 0, stream>>>(src, dst, bcur, staged,
                                                  W1, W2, W_ih, Wt1, Wt2, Wihb,
                                                  E, nb_bin);
    scatter_csr<<<NB, blk, 0, stream>>>(staged, bcur, off, dinv, rec, N, E, NB);

    // ---- layer 1 ----
    gemm_mfma<<<dim3(nb_g, 1), blk, 0, stream>>>(x, Wt1, A, N, 0, 0, 0);
    aggregate<<<nb_ag, blk, 0, stream>>>(A, dinv, off, rec, b1, B1b, N, 1);

    // ---- layer 2 ----
    gemm_mfma<<<dim3(nb_g, 1), blk, 0, stream>>>(B1b, Wt2, A, N, 1, 0, 0);
    aggregate<<<nb_ag, blk, 0, stream>>>(A, dinv, off, rec, b2, B2b, N, 0);

    // ---- head ----
    pool_mean<<<G, blk, 0, stream>>>(B2b, batch, gbuf, N, G);
    gemm_mfma<<<dim3((G + 63) / 64, 3), blk, 0, stream>>>(gbuf, Wihb, gib, G, 0,
                                                          128 * 128, G * DHID);
    gate_ln_head<<<G, dim3(128), 0, stream>>>(gib, b_ih, b_hh, W_lin, b_lin, out, G);
}

// Round 13
// 341.233 us; speedup vs baseline: 2.5388x; 2.5388x over previous
//
#include <hip/hip_runtime.h>
#include <hip/hip_bf16.h>
#include <math.h>

#define DHID 128
#define SH 8                 // nodes per bucket = 256
#define BIN_T 8192           // edges per bin_edges block
#define CAPSH 13             // staged capacity per bucket = 8192 (avg fill ~4096)

typedef __attribute__((ext_vector_type(8))) short bf16x8;
typedef __attribute__((ext_vector_type(4))) float f32x4;

__device__ __forceinline__ int atomAddI(int* p, int v) {
    return __hip_atomic_fetch_add(p, v, __ATOMIC_RELAXED, __HIP_MEMORY_SCOPE_AGENT);
}
__device__ __forceinline__ float bf_lo(unsigned u) { return __uint_as_float(u << 16); }
__device__ __forceinline__ float bf_hi(unsigned u) { return __uint_as_float(u & 0xffff0000u); }
__device__ __forceinline__ float bf_us(unsigned short u) { return __uint_as_float((unsigned)u << 16); }
__device__ __forceinline__ unsigned short bf16_1(float f) {
    unsigned u = __float_as_uint(f);
    u += 0x7fffu + ((u >> 16) & 1u);   // RNE
    return (unsigned short)(u >> 16);
}
__device__ __forceinline__ unsigned pack_bf16x2(float a, float b) {
    unsigned ua = __float_as_uint(a);
    unsigned ub = __float_as_uint(b);
    ua = (ua + 0x7fffu + ((ua >> 16) & 1u)) >> 16;
    ub = (ub + 0x7fffu + ((ub >> 16) & 1u)) & 0xffff0000u;
    return ua | ub;
}

// ---- phase 1 (three-phase per block): LDS histogram -> chunk reservation -> write ----
// Global atomics only once per (block, bucket): ~200 blocks x 391 buckets.
// blocks >= nb_bin do the weight bf16 prep (independent work folded in).
// staged record: src (bits 0..23) | dst-within-bucket (bits 24..31)
__global__ __launch_bounds__(256) void bin_edges(const int* __restrict__ src,
                                                 const int* __restrict__ dst,
                                                 int* __restrict__ bcur,
                                                 unsigned* __restrict__ staged,
                                                 const float* __restrict__ W1,
                                                 const float* __restrict__ W2,
                                                 const float* __restrict__ Wih,
                                                 unsigned short* __restrict__ Wt1,
                                                 unsigned short* __restrict__ Wt2,
                                                 unsigned short* __restrict__ Wihb,
                                                 int E, int NB, int nb_bin) {
    int t = threadIdx.x;
    if (blockIdx.x >= nb_bin) {
        int idx = (blockIdx.x - nb_bin) * 256 + t;
        if (idx < 16384) {
            int k = idx >> 7, n = idx & 127;
            Wt1[n * 128 + k] = bf16_1(W1[idx]);
        } else if (idx < 32768) {
            int j = idx - 16384;
            int k = j >> 7, n = j & 127;
            Wt2[n * 128 + k] = bf16_1(W2[j]);
        } else if (idx < 32768 + 49152) {
            int j = idx - 32768;
            Wihb[j] = bf16_1(Wih[j]);
        }
        return;
    }
    __shared__ int lh[512], lbase[512], lcur[512];
    int e0 = blockIdx.x * BIN_T;
    int eend = min(e0 + BIN_T, E);
    for (int i = t; i < NB; i += 256) { lh[i] = 0; lcur[i] = 0; }
    __syncthreads();
    for (int e = e0 + t; e < eend; e += 256)
        atomicAdd(&lh[dst[e] >> SH], 1);
    __syncthreads();
    for (int i = t; i < NB; i += 256)
        lbase[i] = lh[i] ? atomAddI(&bcur[i], lh[i]) : 0;
    __syncthreads();
    for (int e = e0 + t; e < eend; e += 256) {
        int d = dst[e];
        int b = d >> SH;
        int pos = lbase[b] + atomicAdd(&lcur[b], 1);
        staged[((size_t)b << CAPSH) + pos] =
            (unsigned)src[e] | ((unsigned)(d & ((1 << SH) - 1)) << 24);
    }
}

// ---- phase 2: per bucket — global base (reduction over bcur), node histogram
//      + scan (-> off, dinv), then scatter into the bucket's CSR window ----
__global__ __launch_bounds__(256) void scatter_csr(const unsigned* __restrict__ staged,
                                                   const int* __restrict__ bcur,
                                                   int* __restrict__ off,
                                                   float* __restrict__ dinv,
                                                   int* __restrict__ rec,
                                                   int N, int E, int NB) {
    __shared__ int sh[256];
    __shared__ int curs[256];
    __shared__ int hist[256];
    int t = threadIdx.x;
    int b = blockIdx.x;
    int node0 = b << SH;

    // base = sum of bcur[0..b-1]
    int s0 = (t < b) ? bcur[t] : 0;
    int s1 = (256 + t < b) ? bcur[256 + t] : 0;
    int s = s0 + s1;
#pragma unroll
    for (int o = 1; o < 64; o <<= 1) s += __shfl_xor(s, o);
    if ((t & 63) == 0) sh[t >> 6] = s;
    __syncthreads();
    int base = sh[0] + sh[1] + sh[2] + sh[3];
    __syncthreads();

    // per-node histogram of this bucket's staged records
    hist[t] = 0;
    __syncthreads();
    int cnt_b = bcur[b];
    const unsigned* st = staged + ((size_t)b << CAPSH);
    for (int j = t; j < cnt_b; j += 256)
        atomicAdd(&hist[st[j] >> 24], 1);
    __syncthreads();
    int v = hist[t];
    sh[t] = v;
    __syncthreads();
#pragma unroll
    for (int o = 1; o < 256; o <<= 1) {
        int x = (t >= o) ? sh[t - o] : 0;
        __syncthreads();
        sh[t] += x;
        __syncthreads();
    }
    int excl = sh[t] - v;
    int node = node0 + t;
    if (node < N) {
        off[node] = base + excl;
        dinv[node] = rsqrtf((float)v + 1.0f);
    }
    if (b == NB - 1 && t == 0) off[N] = E;
    curs[t] = base + excl;
    __syncthreads();
    for (int j = t; j < cnt_b; j += 256) {
        unsigned w = st[j];
        int dl = w >> 24;
        int pos = atomicAdd(&curs[dl], 1);
        rec[pos] = (int)(w & 0xFFFFFFu);
    }
}

// ---------------- MFMA GEMM: Y_bf16[rows,128] = X[rows,128] @ Wt^T ----------------
// 64 rows/block, 4 waves; epilogue via LDS transpose -> coalesced uint4 stores.
__global__ __launch_bounds__(256) void gemm_mfma(const void* __restrict__ Xv,
                                                 const unsigned short* __restrict__ Wt,
                                                 unsigned short* __restrict__ Y,
                                                 int N, int x_is_bf16,
                                                 int wstride, int ystride) {
    __shared__ unsigned short Xs[64 * 136];
    __shared__ unsigned short Ws[128 * 136];
    const int tid = threadIdx.x;
    const unsigned short* Wg = Wt + (size_t)blockIdx.y * wstride;
    unsigned short* Yg = Y + (size_t)blockIdx.y * ystride;

    {
        const uint4* W4 = (const uint4*)Wg;
#pragma unroll
        for (int i = 0; i < 8; i++) {
            int idx = tid + i * 256;
            int r = idx >> 4, c8 = idx & 15;
            *(uint4*)&Ws[r * 136 + c8 * 8] = W4[idx];
        }
    }
    const int row0 = blockIdx.x * 64;
    if (x_is_bf16) {
        const uint4* X4 = (const uint4*)Xv;
#pragma unroll
        for (int i = 0; i < 4; i++) {
            int idx = tid + i * 256;
            int r = idx >> 4, c8 = idx & 15;
            uint4 v = make_uint4(0u, 0u, 0u, 0u);
            if (row0 + r < N) v = X4[(size_t)(row0 + r) * 16 + c8];
            *(uint4*)&Xs[r * 136 + c8 * 8] = v;
        }
    } else {
        const float4* X4 = (const float4*)Xv;
#pragma unroll
        for (int i = 0; i < 8; i++) {
            int idx = tid + i * 256;
            int r = idx >> 5, c4 = idx & 31;
            float4 v = make_float4(0.f, 0.f, 0.f, 0.f);
            if (row0 + r < N) v = X4[(size_t)(row0 + r) * 32 + c4];
            uint2 pk = make_uint2(pack_bf16x2(v.x, v.y), pack_bf16x2(v.z, v.w));
            *(uint2*)&Xs[r * 136 + c4 * 4] = pk;
        }
    }
    __syncthreads();

    const int lane = tid & 63;
    const int wv = tid >> 6;
    const int m = lane & 15, quad = lane >> 4;
    const int wrow = wv * 16;

    f32x4 acc[8];
#pragma unroll
    for (int i = 0; i < 8; i++) acc[i] = (f32x4){0.f, 0.f, 0.f, 0.f};

#pragma unroll
    for (int kc = 0; kc < 4; kc++) {
        bf16x8 a = *(const bf16x8*)&Xs[(wrow + m) * 136 + kc * 32 + quad * 8];
#pragma unroll
        for (int nt = 0; nt < 8; nt++) {
            bf16x8 b = *(const bf16x8*)&Ws[(nt * 16 + m) * 136 + kc * 32 + quad * 8];
            acc[nt] = __builtin_amdgcn_mfma_f32_16x16x32_bf16(a, b, acc[nt], 0, 0, 0);
        }
    }

#pragma unroll
    for (int r = 0; r < 4; r++) {
        int lrow = wrow + quad * 4 + r;
#pragma unroll
        for (int nt = 0; nt < 8; nt++)
            Xs[lrow * 136 + nt * 16 + m] = bf16_1(acc[nt][r]);
    }
    __syncthreads();
#pragma unroll
    for (int i = 0; i < 4; i++) {
        int idx = tid + i * 256;
        int r = idx >> 4, c8 = idx & 15;
        if (row0 + r < N)
            *(uint4*)&Yg[(size_t)(row0 + r) * DHID + c8 * 8] =
                *(const uint4*)&Xs[r * 136 + c8 * 8];
    }
}

// ---------------- CSR aggregate: quarter-wave uint4 gathers, bf16 out ----------------
// float2 accumulators (packed f32 math) + software-pipelined rec loads.
__global__ __launch_bounds__(256) void aggregate(const unsigned short* __restrict__ A,
                                                 const float* __restrict__ dinv,
                                                 const int* __restrict__ off,
                                                 const int* __restrict__ rec,
                                                 const float* __restrict__ bias,
                                                 unsigned short* __restrict__ Bout,
                                                 int N, int mode) {
    int node = blockIdx.x * 4 + (threadIdx.x >> 6);
    if (node >= N) return;
    int lane = threadIdx.x & 63;
    int q  = lane >> 4;
    int ql = lane & 15;
    float di = dinv[node];
    float2 acc[4];
    if (q == 0) {
        float s = di * di;
        uint4 v = ((const uint4*)(A + (size_t)node * DHID))[ql];
        const float4* bb = (const float4*)(bias + ql * 8);
        float4 b0 = bb[0], b1 = bb[1];
        acc[0] = make_float2(bf_lo(v.x) * s + b0.x, bf_hi(v.x) * s + b0.y);
        acc[1] = make_float2(bf_lo(v.y) * s + b0.z, bf_hi(v.y) * s + b0.w);
        acc[2] = make_float2(bf_lo(v.z) * s + b1.x, bf_hi(v.z) * s + b1.y);
        acc[3] = make_float2(bf_lo(v.w) * s + b1.z, bf_hi(v.w) * s + b1.w);
    } else {
#pragma unroll
        for (int i = 0; i < 4; i++) acc[i] = make_float2(0.f, 0.f);
    }
    int j = off[node] + q;
    int jend = off[node + 1];
    if (j + 4 < jend) {
        int s0 = rec[j], s1 = rec[j + 4];
        for (; j + 12 < jend; j += 8) {
            int n0 = rec[j + 8], n1 = rec[j + 12];      // prefetch next pair
            uint4 v0 = ((const uint4*)(A + (size_t)s0 * DHID))[ql];
            uint4 v1 = ((const uint4*)(A + (size_t)s1 * DHID))[ql];
            float w0 = dinv[s0] * di;
            float w1 = dinv[s1] * di;
            acc[0].x += bf_lo(v0.x) * w0 + bf_lo(v1.x) * w1;
            acc[0].y += bf_hi(v0.x) * w0 + bf_hi(v1.x) * w1;
            acc[1].x += bf_lo(v0.y) * w0 + bf_lo(v1.y) * w1;
            acc[1].y += bf_hi(v0.y) * w0 + bf_hi(v1.y) * w1;
            acc[2].x += bf_lo(v0.z) * w0 + bf_lo(v1.z) * w1;
            acc[2].y += bf_hi(v0.z) * w0 + bf_hi(v1.z) * w1;
            acc[3].x += bf_lo(v0.w) * w0 + bf_lo(v1.w) * w1;
            acc[3].y += bf_hi(v0.w) * w0 + bf_hi(v1.w) * w1;
            s0 = n0; s1 = n1;
        }
        {
            uint4 v0 = ((const uint4*)(A + (size_t)s0 * DHID))[ql];
            uint4 v1 = ((const uint4*)(A + (size_t)s1 * DHID))[ql];
            float w0 = dinv[s0] * di;
            float w1 = dinv[s1] * di;
            acc[0].x += bf_lo(v0.x) * w0 + bf_lo(v1.x) * w1;
            acc[0].y += bf_hi(v0.x) * w0 + bf_hi(v1.x) * w1;
            acc[1].x += bf_lo(v0.y) * w0 + bf_lo(v1.y) * w1;
            acc[1].y += bf_hi(v0.y) * w0 + bf_hi(v1.y) * w1;
            acc[2].x += bf_lo(v0.z) * w0 + bf_lo(v1.z) * w1;
            acc[2].y += bf_hi(v0.z) * w0 + bf_hi(v1.z) * w1;
            acc[3].x += bf_lo(v0.w) * w0 + bf_lo(v1.w) * w1;
            acc[3].y += bf_hi(v0.w) * w0 + bf_hi(v1.w) * w1;
            j += 8;
        }
    }
    if (j < jend) {
        int s0 = rec[j];
        uint4 v0 = ((const uint4*)(A + (size_t)s0 * DHID))[ql];
        float w0 = dinv[s0] * di;
        acc[0].x += bf_lo(v0.x) * w0;
        acc[0].y += bf_hi(v0.x) * w0;
        acc[1].x += bf_lo(v0.y) * w0;
        acc[1].y += bf_hi(v0.y) * w0;
        acc[2].x += bf_lo(v0.z) * w0;
        acc[2].y += bf_hi(v0.z) * w0;
        acc[3].x += bf_lo(v0.w) * w0;
        acc[3].y += bf_hi(v0.w) * w0;
    }
#pragma unroll
    for (int i = 0; i < 4; i++) {
        acc[i].x += __shfl_xor(acc[i].x, 16);
        acc[i].y += __shfl_xor(acc[i].y, 16);
        acc[i].x += __shfl_xor(acc[i].x, 32);
        acc[i].y += __shfl_xor(acc[i].y, 32);
    }
    if (q == 0) {
        if (mode == 1) {
#pragma unroll
            for (int i = 0; i < 4; i++) {
                acc[i].x = fmaxf(acc[i].x, 0.f);
                acc[i].y = fmaxf(acc[i].y, 0.f);
            }
        }
        uint4 pk;
        pk.x = pack_bf16x2(acc[0].x, acc[0].y);
        pk.y = pack_bf16x2(acc[1].x, acc[1].y);
        pk.z = pack_bf16x2(acc[2].x, acc[2].y);
        pk.w = pack_bf16x2(acc[3].x, acc[3].y);
        ((uint4*)(Bout + (size_t)node * DHID))[ql] = pk;
    }
}

// ---------------- pool: per-graph mean (bf16 input) ----------------
__global__ __launch_bounds__(256) void pool_mean(const unsigned short* __restrict__ B,
                                                 const int* __restrict__ batch,
                                                 float* __restrict__ g, int N, int G) {
    __shared__ int se[2];
    __shared__ float red[128];
    const int t = threadIdx.x;
    const int gr = blockIdx.x;
    if (t < 2) {
        int target = gr + t, lo = 0, hi = N;
        while (lo < hi) {
            int mid = (lo + hi) >> 1;
            if (batch[mid] < target) lo = mid + 1; else hi = mid;
        }
        se[t] = lo;
    }
    __syncthreads();
    const int s = se[0], e = se[1];
    const int col = t & 127, rh = t >> 7;
    float sum = 0.f;
    for (int r = s + rh; r < e; r += 2) sum += bf_us(B[(size_t)r * DHID + col]);
    if (rh == 1) red[col] = sum;
    __syncthreads();
    if (rh == 0) {
        float tot = sum + red[col];
        g[(size_t)gr * DHID + col] = tot / fmaxf((float)(e - s), 1.0f);
    }
}

// ---------------- gates + relu + layernorm + linear ----------------
__global__ __launch_bounds__(128) void gate_ln_head(const unsigned short* __restrict__ gi,
                                                    const float* __restrict__ b_ih,
                                                    const float* __restrict__ b_hh,
                                                    const float* __restrict__ W_lin,
                                                    const float* __restrict__ b_lin,
                                                    float* __restrict__ out, int G) {
    __shared__ float red[2];
    const int t = threadIdx.x;
    const int g = blockIdx.x;

    float d0 = bf_us(gi[(size_t)g * DHID + t]);
    float d1 = bf_us(gi[(size_t)(G + g) * DHID + t]);
    float d2 = bf_us(gi[(size_t)(2 * G + g) * DHID + t]);

    float rg = 1.f / (1.f + expf(-(d0 + b_ih[t] + b_hh[t])));
    float zg = 1.f / (1.f + expf(-(d1 + b_ih[128 + t] + b_hh[128 + t])));
    float ng = tanhf(d2 + b_ih[256 + t] + rg * b_hh[256 + t]);
    float y = fmaxf((1.f - zg) * ng, 0.f);

    auto blockSum = [&](float v) -> float {
#pragma unroll
        for (int o = 1; o < 64; o <<= 1) v += __shfl_xor(v, o);
        __syncthreads();
        if ((t & 63) == 0) red[t >> 6] = v;
        __syncthreads();
        return red[0] + red[1];
    };

    float mu = blockSum(y) * (1.f / 128.f);
    float dy = y - mu;
    float var = blockSum(dy * dy) * (1.f / 128.f);
    float yn = dy * rsqrtf(var + 1e-5f);
    float tot = blockSum(yn * W_lin[t]);
    if (t == 0) out[g] = tot + b_lin[0];
}

extern "C" void kernel_launch(void* const* d_in, const int* in_sizes, int n_in,
                              void* d_out, int out_size, void* d_ws, size_t ws_size,
                              hipStream_t stream) {
    const float* x     = (const float*)d_in[0];
    const int*   ei    = (const int*)d_in[1];
    const int*   batch = (const int*)d_in[2];
    const float* W1    = (const float*)d_in[3];
    const float* b1    = (const float*)d_in[4];
    const float* W2    = (const float*)d_in[5];
    const float* b2    = (const float*)d_in[6];
    const float* W_ih  = (const float*)d_in[7];
    // d_in[8] = W_hh unused (h0 == 0)
    const float* b_ih  = (const float*)d_in[9];
    const float* b_hh  = (const float*)d_in[10];
    const float* W_lin = (const float*)d_in[11];
    const float* b_lin = (const float*)d_in[12];
    float* out = (float*)d_out;

    const int N = in_sizes[0] / DHID;
    const int E = in_sizes[1] / 2;
    const int G = out_size;
    const int* src = ei;
    const int* dst = ei + E;
    const int NB = (N + (1 << SH) - 1) >> SH;   // buckets (<= 512)

    auto align256 = [](size_t v) { return (v + 255) & ~(size_t)255; };
    char* p = (char*)d_ws;
    size_t used = 0;
    auto carve = [&](size_t bytes) -> char* {
        char* q = p + used;
        used += align256(bytes);
        return q;
    };

    int*   off    = (int*)carve(((size_t)N + 1) * 4);
    int*   bcur   = (int*)carve(512 * 4);
    float* dinv   = (float*)carve((size_t)N * 4);
    unsigned* staged = (unsigned*)carve(((size_t)NB << CAPSH) * 4);
    int*   rec    = (int*)carve((size_t)E * 4);
    float* gbuf   = (float*)carve((size_t)G * DHID * 4);
    unsigned short* Wt1  = (unsigned short*)carve((size_t)128 * 128 * 2);
    unsigned short* Wt2  = (unsigned short*)carve((size_t)128 * 128 * 2);
    unsigned short* Wihb = (unsigned short*)carve((size_t)3 * 128 * 128 * 2);
    unsigned short* gib  = (unsigned short*)carve((size_t)3 * G * DHID * 2);
    unsigned short* A    = (unsigned short*)carve((size_t)N * DHID * 2);   // bf16
    unsigned short* B1b  = (unsigned short*)carve((size_t)N * DHID * 2);   // bf16, relu'd
    size_t matB = (size_t)N * DHID * 2;
    unsigned short* B2b;
    if (ws_size >= used + matB) {
        B2b = (unsigned short*)carve(matB);
    } else {
        B2b = (unsigned short*)d_in[0];   // x fully consumed by gemm-1 before agg-2 writes
    }

    dim3 blk(256);
    int nb_g  = (N + 63) / 64;
    int nb_ag = (N + 3) / 4;
    int nb_bin = (E + BIN_T - 1) / BIN_T;
    int nb_wp  = (81920 + 255) / 256;

    // ---- CSR build (3 dispatches; weight prep folded into bin_edges) ----
    hipMemsetAsync(bcur, 0, (size_t)NB * 4, stream);
    bin_edges<<<nb_bin + nb_wp, blk, 0, stream>>>(src, dst, bcur, staged,
                                                  W1, W2, W_ih, Wt1, Wt2, Wihb,
                                                  E, NB, nb_bin);
    scatter_csr<<<NB, blk, 0, stream>>>(staged, bcur, off, dinv, rec, N, E, NB);

    // ---- layer 1 ----
    gemm_mfma<<<dim3(nb_g, 1), blk, 0, stream>>>(x, Wt1, A, N, 0, 0, 0);
    aggregate<<<nb_ag, blk, 0, stream>>>(A, dinv, off, rec, b1, B1b, N, 1);

    // ---- layer 2 ----
    gemm_mfma<<<dim3(nb_g, 1), blk, 0, stream>>>(B1b, Wt2, A, N, 1, 0, 0);
    aggregate<<<nb_ag, blk, 0, stream>>>(A, dinv, off, rec, b2, B2b, N, 0);

    // ---- head ----
    pool_mean<<<G, blk, 0, stream>>>(B2b, batch, gbuf, N, G);
    gemm_mfma<<<dim3((G + 63) / 64, 3), blk, 0, stream>>>(gbuf, Wihb, gib, G, 0,
                                                          128 * 128, G * DHID);
    gate_ln_head<<<G, dim3(128), 0, stream>>>(gib, b_ih, b_hh, W_lin, b_lin, out, G);
}

// Round 14
// 340.533 us; speedup vs baseline: 2.5441x; 1.0021x over previous
//
#include <hip/hip_runtime.h>
#include <hip/hip_bf16.h>
#include <math.h>

#define DHID 128
#define SH 8                 // nodes per bucket = 256
#define BIN_T 8192           // edges per bin_edges block
#define CAPSH 13             // staged capacity per bucket = 8192 (avg fill ~4096)
#define SRC_SH 13            // src-range granularity = 8192 nodes (~2MB bf16 rows); N<=131072

typedef __attribute__((ext_vector_type(8))) short bf16x8;
typedef __attribute__((ext_vector_type(4))) float f32x4;

__device__ __forceinline__ int atomAddI(int* p, int v) {
    return __hip_atomic_fetch_add(p, v, __ATOMIC_RELAXED, __HIP_MEMORY_SCOPE_AGENT);
}
__device__ __forceinline__ float bf_lo(unsigned u) { return __uint_as_float(u << 16); }
__device__ __forceinline__ float bf_hi(unsigned u) { return __uint_as_float(u & 0xffff0000u); }
__device__ __forceinline__ float bf_us(unsigned short u) { return __uint_as_float((unsigned)u << 16); }
__device__ __forceinline__ unsigned short bf16_1(float f) {
    unsigned u = __float_as_uint(f);
    u += 0x7fffu + ((u >> 16) & 1u);   // RNE
    return (unsigned short)(u >> 16);
}
__device__ __forceinline__ unsigned pack_bf16x2(float a, float b) {
    unsigned ua = __float_as_uint(a);
    unsigned ub = __float_as_uint(b);
    ua = (ua + 0x7fffu + ((ua >> 16) & 1u)) >> 16;
    ub = (ub + 0x7fffu + ((ub >> 16) & 1u)) & 0xffff0000u;
    return ua | ub;
}

// ---- phase 1 (three-phase per block): LDS histogram -> chunk reservation -> write ----
// blocks >= nb_bin do the weight bf16 prep (independent work folded in).
// staged record: src (bits 0..23) | dst-within-bucket (bits 24..31)
__global__ __launch_bounds__(256) void bin_edges(const int* __restrict__ src,
                                                 const int* __restrict__ dst,
                                                 int* __restrict__ bcur,
                                                 unsigned* __restrict__ staged,
                                                 const float* __restrict__ W1,
                                                 const float* __restrict__ W2,
                                                 const float* __restrict__ Wih,
                                                 unsigned short* __restrict__ Wt1,
                                                 unsigned short* __restrict__ Wt2,
                                                 unsigned short* __restrict__ Wihb,
                                                 int E, int NB, int nb_bin) {
    int t = threadIdx.x;
    if (blockIdx.x >= nb_bin) {
        int idx = (blockIdx.x - nb_bin) * 256 + t;
        if (idx < 16384) {
            int k = idx >> 7, n = idx & 127;
            Wt1[n * 128 + k] = bf16_1(W1[idx]);
        } else if (idx < 32768) {
            int j = idx - 16384;
            int k = j >> 7, n = j & 127;
            Wt2[n * 128 + k] = bf16_1(W2[j]);
        } else if (idx < 32768 + 49152) {
            int j = idx - 32768;
            Wihb[j] = bf16_1(Wih[j]);
        }
        return;
    }
    __shared__ int lh[512], lbase[512], lcur[512];
    int e0 = blockIdx.x * BIN_T;
    int eend = min(e0 + BIN_T, E);
    for (int i = t; i < NB; i += 256) { lh[i] = 0; lcur[i] = 0; }
    __syncthreads();
    for (int e = e0 + t; e < eend; e += 256)
        atomicAdd(&lh[dst[e] >> SH], 1);
    __syncthreads();
    for (int i = t; i < NB; i += 256)
        lbase[i] = lh[i] ? atomAddI(&bcur[i], lh[i]) : 0;
    __syncthreads();
    for (int e = e0 + t; e < eend; e += 256) {
        int d = dst[e];
        int b = d >> SH;
        int pos = lbase[b] + atomicAdd(&lcur[b], 1);
        staged[((size_t)b << CAPSH) + pos] =
            (unsigned)src[e] | ((unsigned)(d & ((1 << SH) - 1)) << 24);
    }
}

// ---- phase 2: per bucket — counting sort by (dst-local, src-range) ----
// key = (dl<<4) | (src>>SRC_SH). Thread t owns keys [t*16, t*16+16) == node t's
// 16 range-counters, so its chunk sum is node t's degree and its scan prefix is
// node t's CSR offset. Result: each node's edge list is sorted by src-range ->
// the whole GPU gathers from ~one 2MB range at a time (L2-resident).
__global__ __launch_bounds__(256) void scatter_csr(const unsigned* __restrict__ staged,
                                                   const int* __restrict__ bcur,
                                                   int* __restrict__ off,
                                                   float* __restrict__ dinv,
                                                   int* __restrict__ rec,
                                                   int N, int E, int NB) {
    __shared__ int hist[4096];
    __shared__ int sh[256];
    int t = threadIdx.x;
    int b = blockIdx.x;
    int node0 = b << SH;

    // base = sum of bcur[0..b-1]
    int s0 = (t < b) ? bcur[t] : 0;
    int s1 = (256 + t < b) ? bcur[256 + t] : 0;
    int s = s0 + s1;
#pragma unroll
    for (int o = 1; o < 64; o <<= 1) s += __shfl_xor(s, o);
    if ((t & 63) == 0) sh[t >> 6] = s;
    __syncthreads();
    int base = sh[0] + sh[1] + sh[2] + sh[3];
    __syncthreads();

    // histogram over 4096 keys
    for (int i = t; i < 4096; i += 256) hist[i] = 0;
    __syncthreads();
    int cnt_b = bcur[b];
    const unsigned* st = staged + ((size_t)b << CAPSH);
    for (int j = t; j < cnt_b; j += 256) {
        unsigned w = st[j];
        int key = (int)((w >> 24) << 4) | (int)((w & 0xFFFFFFu) >> SRC_SH);
        atomicAdd(&hist[key], 1);
    }
    __syncthreads();

    // hierarchical exclusive scan: thread t scans its 16 keys sequentially
    int loc[16];
    int run = 0;
    int base16 = t * 16;
#pragma unroll
    for (int i = 0; i < 16; i++) { loc[i] = run; run += hist[base16 + i]; }
    sh[t] = run;
    __syncthreads();
#pragma unroll
    for (int o = 1; o < 256; o <<= 1) {
        int x = (t >= o) ? sh[t - o] : 0;
        __syncthreads();
        sh[t] += x;
        __syncthreads();
    }
    int excl = sh[t] - run;          // node t's offset within bucket
#pragma unroll
    for (int i = 0; i < 16; i++) hist[base16 + i] = base + excl + loc[i];

    int node = node0 + t;
    if (node < N) {
        off[node] = base + excl;
        dinv[node] = rsqrtf((float)run + 1.0f);
    }
    if (b == NB - 1 && t == 0) off[N] = E;
    __syncthreads();

    // scatter in sorted order via per-key cursors
    for (int j = t; j < cnt_b; j += 256) {
        unsigned w = st[j];
        int key = (int)((w >> 24) << 4) | (int)((w & 0xFFFFFFu) >> SRC_SH);
        int pos = atomicAdd(&hist[key], 1);
        rec[pos] = (int)(w & 0xFFFFFFu);
    }
}

// ---------------- MFMA GEMM: Y_bf16[rows,128] = X[rows,128] @ Wt^T ----------------
// 64 rows/block, 4 waves; epilogue via LDS transpose -> coalesced uint4 stores.
__global__ __launch_bounds__(256) void gemm_mfma(const void* __restrict__ Xv,
                                                 const unsigned short* __restrict__ Wt,
                                                 unsigned short* __restrict__ Y,
                                                 int N, int x_is_bf16,
                                                 int wstride, int ystride) {
    __shared__ unsigned short Xs[64 * 136];
    __shared__ unsigned short Ws[128 * 136];
    const int tid = threadIdx.x;
    const unsigned short* Wg = Wt + (size_t)blockIdx.y * wstride;
    unsigned short* Yg = Y + (size_t)blockIdx.y * ystride;

    {
        const uint4* W4 = (const uint4*)Wg;
#pragma unroll
        for (int i = 0; i < 8; i++) {
            int idx = tid + i * 256;
            int r = idx >> 4, c8 = idx & 15;
            *(uint4*)&Ws[r * 136 + c8 * 8] = W4[idx];
        }
    }
    const int row0 = blockIdx.x * 64;
    if (x_is_bf16) {
        const uint4* X4 = (const uint4*)Xv;
#pragma unroll
        for (int i = 0; i < 4; i++) {
            int idx = tid + i * 256;
            int r = idx >> 4, c8 = idx & 15;
            uint4 v = make_uint4(0u, 0u, 0u, 0u);
            if (row0 + r < N) v = X4[(size_t)(row0 + r) * 16 + c8];
            *(uint4*)&Xs[r * 136 + c8 * 8] = v;
        }
    } else {
        const float4* X4 = (const float4*)Xv;
#pragma unroll
        for (int i = 0; i < 8; i++) {
            int idx = tid + i * 256;
            int r = idx >> 5, c4 = idx & 31;
            float4 v = make_float4(0.f, 0.f, 0.f, 0.f);
            if (row0 + r < N) v = X4[(size_t)(row0 + r) * 32 + c4];
            uint2 pk = make_uint2(pack_bf16x2(v.x, v.y), pack_bf16x2(v.z, v.w));
            *(uint2*)&Xs[r * 136 + c4 * 4] = pk;
        }
    }
    __syncthreads();

    const int lane = tid & 63;
    const int wv = tid >> 6;
    const int m = lane & 15, quad = lane >> 4;
    const int wrow = wv * 16;

    f32x4 acc[8];
#pragma unroll
    for (int i = 0; i < 8; i++) acc[i] = (f32x4){0.f, 0.f, 0.f, 0.f};

#pragma unroll
    for (int kc = 0; kc < 4; kc++) {
        bf16x8 a = *(const bf16x8*)&Xs[(wrow + m) * 136 + kc * 32 + quad * 8];
#pragma unroll
        for (int nt = 0; nt < 8; nt++) {
            bf16x8 b = *(const bf16x8*)&Ws[(nt * 16 + m) * 136 + kc * 32 + quad * 8];
            acc[nt] = __builtin_amdgcn_mfma_f32_16x16x32_bf16(a, b, acc[nt], 0, 0, 0);
        }
    }

#pragma unroll
    for (int r = 0; r < 4; r++) {
        int lrow = wrow + quad * 4 + r;
#pragma unroll
        for (int nt = 0; nt < 8; nt++)
            Xs[lrow * 136 + nt * 16 + m] = bf16_1(acc[nt][r]);
    }
    __syncthreads();
#pragma unroll
    for (int i = 0; i < 4; i++) {
        int idx = tid + i * 256;
        int r = idx >> 4, c8 = idx & 15;
        if (row0 + r < N)
            *(uint4*)&Yg[(size_t)(row0 + r) * DHID + c8 * 8] =
                *(const uint4*)&Xs[r * 136 + c8 * 8];
    }
}

// ---------------- CSR aggregate: quarter-wave uint4 gathers, bf16 out ----------------
// float2 accumulators (packed f32 math) + software-pipelined rec loads.
__global__ __launch_bounds__(256) void aggregate(const unsigned short* __restrict__ A,
                                                 const float* __restrict__ dinv,
                                                 const int* __restrict__ off,
                                                 const int* __restrict__ rec,
                                                 const float* __restrict__ bias,
                                                 unsigned short* __restrict__ Bout,
                                                 int N, int mode) {
    int node = blockIdx.x * 4 + (threadIdx.x >> 6);
    if (node >= N) return;
    int lane = threadIdx.x & 63;
    int q  = lane >> 4;
    int ql = lane & 15;
    float di = dinv[node];
    float2 acc[4];
    if (q == 0) {
        float s = di * di;
        uint4 v = ((const uint4*)(A + (size_t)node * DHID))[ql];
        const float4* bb = (const float4*)(bias + ql * 8);
        float4 b0 = bb[0], b1 = bb[1];
        acc[0] = make_float2(bf_lo(v.x) * s + b0.x, bf_hi(v.x) * s + b0.y);
        acc[1] = make_float2(bf_lo(v.y) * s + b0.z, bf_hi(v.y) * s + b0.w);
        acc[2] = make_float2(bf_lo(v.z) * s + b1.x, bf_hi(v.z) * s + b1.y);
        acc[3] = make_float2(bf_lo(v.w) * s + b1.z, bf_hi(v.w) * s + b1.w);
    } else {
#pragma unroll
        for (int i = 0; i < 4; i++) acc[i] = make_float2(0.f, 0.f);
    }
    int j = off[node] + q;
    int jend = off[node + 1];
    if (j + 4 < jend) {
        int s0 = rec[j], s1 = rec[j + 4];
        for (; j + 12 < jend; j += 8) {
            int n0 = rec[j + 8], n1 = rec[j + 12];      // prefetch next pair
            uint4 v0 = ((const uint4*)(A + (size_t)s0 * DHID))[ql];
            uint4 v1 = ((const uint4*)(A + (size_t)s1 * DHID))[ql];
            float w0 = dinv[s0] * di;
            float w1 = dinv[s1] * di;
            acc[0].x += bf_lo(v0.x) * w0 + bf_lo(v1.x) * w1;
            acc[0].y += bf_hi(v0.x) * w0 + bf_hi(v1.x) * w1;
            acc[1].x += bf_lo(v0.y) * w0 + bf_lo(v1.y) * w1;
            acc[1].y += bf_hi(v0.y) * w0 + bf_hi(v1.y) * w1;
            acc[2].x += bf_lo(v0.z) * w0 + bf_lo(v1.z) * w1;
            acc[2].y += bf_hi(v0.z) * w0 + bf_hi(v1.z) * w1;
            acc[3].x += bf_lo(v0.w) * w0 + bf_lo(v1.w) * w1;
            acc[3].y += bf_hi(v0.w) * w0 + bf_hi(v1.w) * w1;
            s0 = n0; s1 = n1;
        }
        {
            uint4 v0 = ((const uint4*)(A + (size_t)s0 * DHID))[ql];
            uint4 v1 = ((const uint4*)(A + (size_t)s1 * DHID))[ql];
            float w0 = dinv[s0] * di;
            float w1 = dinv[s1] * di;
            acc[0].x += bf_lo(v0.x) * w0 + bf_lo(v1.x) * w1;
            acc[0].y += bf_hi(v0.x) * w0 + bf_hi(v1.x) * w1;
            acc[1].x += bf_lo(v0.y) * w0 + bf_lo(v1.y) * w1;
            acc[1].y += bf_hi(v0.y) * w0 + bf_hi(v1.y) * w1;
            acc[2].x += bf_lo(v0.z) * w0 + bf_lo(v1.z) * w1;
            acc[2].y += bf_hi(v0.z) * w0 + bf_hi(v1.z) * w1;
            acc[3].x += bf_lo(v0.w) * w0 + bf_lo(v1.w) * w1;
            acc[3].y += bf_hi(v0.w) * w0 + bf_hi(v1.w) * w1;
            j += 8;
        }
    }
    if (j < jend) {
        int s0 = rec[j];
        uint4 v0 = ((const uint4*)(A + (size_t)s0 * DHID))[ql];
        float w0 = dinv[s0] * di;
        acc[0].x += bf_lo(v0.x) * w0;
        acc[0].y += bf_hi(v0.x) * w0;
        acc[1].x += bf_lo(v0.y) * w0;
        acc[1].y += bf_hi(v0.y) * w0;
        acc[2].x += bf_lo(v0.z) * w0;
        acc[2].y += bf_hi(v0.z) * w0;
        acc[3].x += bf_lo(v0.w) * w0;
        acc[3].y += bf_hi(v0.w) * w0;
    }
#pragma unroll
    for (int i = 0; i < 4; i++) {
        acc[i].x += __shfl_xor(acc[i].x, 16);
        acc[i].y += __shfl_xor(acc[i].y, 16);
        acc[i].x += __shfl_xor(acc[i].x, 32);
        acc[i].y += __shfl_xor(acc[i].y, 32);
    }
    if (q == 0) {
        if (mode == 1) {
#pragma unroll
            for (int i = 0; i < 4; i++) {
                acc[i].x = fmaxf(acc[i].x, 0.f);
                acc[i].y = fmaxf(acc[i].y, 0.f);
            }
        }
        uint4 pk;
        pk.x = pack_bf16x2(acc[0].x, acc[0].y);
        pk.y = pack_bf16x2(acc[1].x, acc[1].y);
        pk.z = pack_bf16x2(acc[2].x, acc[2].y);
        pk.w = pack_bf16x2(acc[3].x, acc[3].y);
        ((uint4*)(Bout + (size_t)node * DHID))[ql] = pk;
    }
}

// ---------------- pool: per-graph mean (bf16 input) ----------------
__global__ __launch_bounds__(256) void pool_mean(const unsigned short* __restrict__ B,
                                                 const int* __restrict__ batch,
                                                 float* __restrict__ g, int N, int G) {
    __shared__ int se[2];
    __shared__ float red[128];
    const int t = threadIdx.x;
    const int gr = blockIdx.x;
    if (t < 2) {
        int target = gr + t, lo = 0, hi = N;
        while (lo < hi) {
            int mid = (lo + hi) >> 1;
            if (batch[mid] < target) lo = mid + 1; else hi = mid;
        }
        se[t] = lo;
    }
    __syncthreads();
    const int s = se[0], e = se[1];
    const int col = t & 127, rh = t >> 7;
    float sum = 0.f;
    for (int r = s + rh; r < e; r += 2) sum += bf_us(B[(size_t)r * DHID + col]);
    if (rh == 1) red[col] = sum;
    __syncthreads();
    if (rh == 0) {
        float tot = sum + red[col];
        g[(size_t)gr * DHID + col] = tot / fmaxf((float)(e - s), 1.0f);
    }
}

// ---------------- gates + relu + layernorm + linear ----------------
__global__ __launch_bounds__(128) void gate_ln_head(const unsigned short* __restrict__ gi,
                                                    const float* __restrict__ b_ih,
                                                    const float* __restrict__ b_hh,
                                                    const float* __restrict__ W_lin,
                                                    const float* __restrict__ b_lin,
                                                    float* __restrict__ out, int G) {
    __shared__ float red[2];
    const int t = threadIdx.x;
    const int g = blockIdx.x;

    float d0 = bf_us(gi[(size_t)g * DHID + t]);
    float d1 = bf_us(gi[(size_t)(G + g) * DHID + t]);
    float d2 = bf_us(gi[(size_t)(2 * G + g) * DHID + t]);

    float rg = 1.f / (1.f + expf(-(d0 + b_ih[t] + b_hh[t])));
    float zg = 1.f / (1.f + expf(-(d1 + b_ih[128 + t] + b_hh[128 + t])));
    float ng = tanhf(d2 + b_ih[256 + t] + rg * b_hh[256 + t]);
    float y = fmaxf((1.f - zg) * ng, 0.f);

    auto blockSum = [&](float v) -> float {
#pragma unroll
        for (int o = 1; o < 64; o <<= 1) v += __shfl_xor(v, o);
        __syncthreads();
        if ((t & 63) == 0) red[t >> 6] = v;
        __syncthreads();
        return red[0] + red[1];
    };

    float mu = blockSum(y) * (1.f / 128.f);
    float dy = y - mu;
    float var = blockSum(dy * dy) * (1.f / 128.f);
    float yn = dy * rsqrtf(var + 1e-5f);
    float tot = blockSum(yn * W_lin[t]);
    if (t == 0) out[g] = tot + b_lin[0];
}

extern "C" void kernel_launch(void* const* d_in, const int* in_sizes, int n_in,
                              void* d_out, int out_size, void* d_ws, size_t ws_size,
                              hipStream_t stream) {
    const float* x     = (const float*)d_in[0];
    const int*   ei    = (const int*)d_in[1];
    const int*   batch = (const int*)d_in[2];
    const float* W1    = (const float*)d_in[3];
    const float* b1    = (const float*)d_in[4];
    const float* W2    = (const float*)d_in[5];
    const float* b2    = (const float*)d_in[6];
    const float* W_ih  = (const float*)d_in[7];
    // d_in[8] = W_hh unused (h0 == 0)
    const float* b_ih  = (const float*)d_in[9];
    const float* b_hh  = (const float*)d_in[10];
    const float* W_lin = (const float*)d_in[11];
    const float* b_lin = (const float*)d_in[12];
    float* out = (float*)d_out;

    const int N = in_sizes[0] / DHID;
    const int E = in_sizes[1] / 2;
    const int G = out_size;
    const int* src = ei;
    const int* dst = ei + E;
    const int NB = (N + (1 << SH) - 1) >> SH;   // buckets (<= 512)

    auto align256 = [](size_t v) { return (v + 255) & ~(size_t)255; };
    char* p = (char*)d_ws;
    size_t used = 0;
    auto carve = [&](size_t bytes) -> char* {
        char* q = p + used;
        used += align256(bytes);
        return q;
    };

    int*   off    = (int*)carve(((size_t)N + 1) * 4);
    int*   bcur   = (int*)carve(512 * 4);
    float* dinv   = (float*)carve((size_t)N * 4);
    unsigned* staged = (unsigned*)carve(((size_t)NB << CAPSH) * 4);
    int*   rec    = (int*)carve((size_t)E * 4);
    float* gbuf   = (float*)carve((size_t)G * DHID * 4);
    unsigned short* Wt1  = (unsigned short*)carve((size_t)128 * 128 * 2);
    unsigned short* Wt2  = (unsigned short*)carve((size_t)128 * 128 * 2);
    unsigned short* Wihb = (unsigned short*)carve((size_t)3 * 128 * 128 * 2);
    unsigned short* gib  = (unsigned short*)carve((size_t)3 * G * DHID * 2);
    unsigned short* A    = (unsigned short*)carve((size_t)N * DHID * 2);   // bf16
    unsigned short* B1b  = (unsigned short*)carve((size_t)N * DHID * 2);   // bf16, relu'd
    size_t matB = (size_t)N * DHID * 2;
    unsigned short* B2b;
    if (ws_size >= used + matB) {
        B2b = (unsigned short*)carve(matB);
    } else {
        B2b = (unsigned short*)d_in[0];   // x fully consumed by gemm-1 before agg-2 writes
    }

    dim3 blk(256);
    int nb_g  = (N + 63) / 64;
    int nb_ag = (N + 3) / 4;
    int nb_bin = (E + BIN_T - 1) / BIN_T;
    int nb_wp  = (81920 + 255) / 256;

    // ---- CSR build (3 dispatches; weight prep folded into bin_edges) ----
    hipMemsetAsync(bcur, 0, (size_t)NB * 4, stream);
    bin_edges<<<nb_bin + nb_wp, blk, 0, stream>>>(src, dst, bcur, staged,
                                                  W1, W2, W_ih, Wt1, Wt2, Wihb,
                                                  E, NB, nb_bin);
    scatter_csr<<<NB, blk, 0, stream>>>(staged, bcur, off, dinv, rec, N, E, NB);

    // ---- layer 1 ----
    gemm_mfma<<<dim3(nb_g, 1), blk, 0, stream>>>(x, Wt1, A, N, 0, 0, 0);
    aggregate<<<nb_ag, blk, 0, stream>>>(A, dinv, off, rec, b1, B1b, N, 1);

    // ---- layer 2 ----
    gemm_mfma<<<dim3(nb_g, 1), blk, 0, stream>>>(B1b, Wt2, A, N, 1, 0, 0);
    aggregate<<<nb_ag, blk, 0, stream>>>(A, dinv, off, rec, b2, B2b, N, 0);

    // ---- head ----
    pool_mean<<<G, blk, 0, stream>>>(B2b, batch, gbuf, N, G);
    gemm_mfma<<<dim3((G + 63) / 64, 3), blk, 0, stream>>>(gbuf, Wihb, gib, G, 0,
                                                          128 * 128, G * DHID);
    gate_ln_head<<<G, dim3(128), 0, stream>>>(gib, b_ih, b_hh, W_lin, b_lin, out, G);
}